// Round 22
// baseline (369.076 us; speedup 1.0000x reference)
//
#include <hip/hip_runtime.h>

typedef _Float16 f16;
typedef __attribute__((ext_vector_type(4))) _Float16 half4;
typedef __attribute__((ext_vector_type(8))) _Float16 half8;
typedef __attribute__((ext_vector_type(4))) float f32x4;
typedef unsigned short u16;

#define MFMA32(a,b,c) __builtin_amdgcn_mfma_f32_16x16x32_f16(a,b,c,0,0,0)
#define MFMA16(a,b,c) __builtin_amdgcn_mfma_f32_16x16x16f16(a,b,c,0,0,0)

// ws layout (f16 element offsets). Lifetime reuse:
//   X region : X (k1->k2), then O (k3a->k3b)
//   QK region: QK (k2->k3a), then G (k3b->k4)
#define W_IN0   0
#define W_OUT0  196608
#define W_PROJ0 262144
#define X0      327680
#define QK0     33882112ull
#define VT0     100990976ull

// exact-grade GELU: erf via A&S 7.1.26 (|eps|<=1.5e-7)
__device__ __forceinline__ float gelu_f(float x) {
    float z = x * 0.70710678118f;
    float az = fabsf(z);
    float t = 1.f / (1.f + 0.3275911f * az);
    float e = __expf(-z * z);
    float poly = ((((1.061405429f * t - 1.453152027f) * t + 1.421413741f) * t
                   - 0.284496736f) * t + 0.254829592f) * t;
    float er = 1.f - poly * e;
    er = copysignf(er, z);
    return 0.5f * x * (1.f + er);
}

// ---------------- k0: cast weights to f16; build k2-geometry images for w_out/w_proj ----
__global__ void k0_cast(const float* __restrict__ iw, const float* __restrict__ ow,
                        const float* __restrict__ pw, f16* __restrict__ W) {
    int i = blockIdx.x * 256 + threadIdx.x;
    if (i < 196608) W[W_IN0 + i] = (f16)iw[i];
    if (i < 16384) {
        const int s = i & 8191;
        const float* src = (i < 8192) ? ow : pw;
        f16* dst = W + ((i < 8192) ? W_OUT0 : W_PROJ0);
        const int g  = s & 3;
        const int r  = (s >> 2) & 31;
        const int kc = (s >> 7) & 7;
        const int ch = s >> 10;
        const int R = ch * 32 + r;
        const int c0 = kc * 32 + g * 4;
        f32x4 v0 = *(const f32x4*)(src + R * 256 + c0);
        f32x4 v1 = *(const f32x4*)(src + R * 256 + c0 + 16);
        half8 o;
#pragma unroll
        for (int j = 0; j < 4; ++j) { o[j] = (f16)v0[j]; o[j + 4] = (f16)v1[j]; }
        const int sg = g ^ ((r >> 1) & 3);
        *(half8*)(dst + ch * 8192 + kc * 1024 + r * 32 + sg * 8) = o;
    }
}

// ---------------- k1: NCHW gather + LayerNorm -> X[t][256] f16, k4-geometry ----------------
__global__ __launch_bounds__(256, 2)
void k1_pack(const float* __restrict__ feat, const float* __restrict__ lnw,
             const float* __restrict__ lnb, f16* __restrict__ X) {
    __shared__ float redS[256], redQ[256];
    const int tid = threadIdx.x;
    const int w = tid & 127, cq = tid >> 7;
    const int bid = blockIdx.x;
    const int bb = bid >> 7, h = bid & 127;
    const int c0 = cq * 128;
    const bool ok = (h < 127) && (w < 127);
    const size_t bbase = (size_t)bb * (256 * 127 * 127);
    const float* p0 = feat + bbase + (size_t)c0 * 16129 + (size_t)h * 127 + w;

    half8 ov[16];                      // 128 channels as f16
    float s = 0.f, s2 = 0.f;
    if (ok) {
#pragma unroll
        for (int i = 0; i < 16; ++i) {
            half8 hv;
#pragma unroll
            for (int j = 0; j < 8; ++j) {
                float v = p0[(size_t)(i * 8 + j) * 16129];
                s += v; s2 += v * v; hv[j] = (f16)v;
            }
            ov[i] = hv;
        }
    } else {
#pragma unroll
        for (int i = 0; i < 16; ++i) {
            half8 hv;
#pragma unroll
            for (int j = 0; j < 8; ++j) hv[j] = (f16)0.f;
            ov[i] = hv;
        }
    }
    redS[tid] = s; redQ[tid] = s2;
    __syncthreads();
    float st = redS[w] + redS[w + 128];
    float qt = redQ[w] + redQ[w + 128];
    float mu = st * (1.f / 256.f);
    float rs = rsqrtf(qt * (1.f / 256.f) - mu * mu + 1e-5f);

    const int wi = h >> 2, hh = h & 3;
    const int jh = w >> 5, wl4 = (w >> 2) & 7, e = w & 3;
    const size_t t = ((size_t)((bb * 32 + wi) * 4 + jh)) * 128 + wl4 * 16 + hh * 4 + e;
    f16* xrow = X + t * 256 + c0;
#pragma unroll
    for (int i = 0; i < 16; ++i) {
        f32x4 lw0 = *(const f32x4*)(lnw + c0 + i * 8);
        f32x4 lw1 = *(const f32x4*)(lnw + c0 + i * 8 + 4);
        f32x4 lb0 = *(const f32x4*)(lnb + c0 + i * 8);
        f32x4 lb1 = *(const f32x4*)(lnb + c0 + i * 8 + 4);
        half8 o;
#pragma unroll
        for (int j = 0; j < 4; ++j) {
            o[j]     = (f16)(((float)ov[i][j]     - mu) * rs * lw0[j] + lb0[j]);
            o[j + 4] = (f16)(((float)ov[i][j + 4] - mu) * rs * lw1[j] + lb1[j]);
        }
        *(half8*)(xrow + i * 8) = o;
    }
}

// ---------------- k2: QKV GEMM  X[131072x256] @ in_w^T -> QK / VT ----------------
// R20 T4 pipeline (triple buffer, counted vmcnt, raw barrier) + T5 setprio (frozen).
__global__ __launch_bounds__(512, 2)
void k2_qkv(const f16* __restrict__ X, const f16* __restrict__ win,
            const float* __restrict__ inb, f16* __restrict__ QK, f16* __restrict__ VT) {
    __shared__ __align__(16) char sm[73728];   // 3 bufs x (A 16K | B 8K)
    const int tid = threadIdx.x, lane = tid & 63, wv = tid >> 6;   // 8 waves
    const int nwg = gridDim.x;                 // 3072, divisible by 8
    const int bid = (blockIdx.x & 7) * (nwg >> 3) + (blockIdx.x >> 3);
    const int mt = bid / 6, nb = bid % 6;
    const size_t Mbase = (size_t)mt * 256;
    const int n0 = nb * 128;
    const int wm = wv >> 1, wn = wv & 1;       // 4 M-groups x 2 N-groups
    const int c = lane & 15, g = lane >> 4;
    const int chs = (lane & 3) ^ ((lane >> 3) & 3);   // involution source chunk

    f32x4 acc[4][4];
#pragma unroll
    for (int a = 0; a < 4; ++a)
#pragma unroll
        for (int b = 0; b < 4; ++b) acc[a][b] = f32x4{0.f, 0.f, 0.f, 0.f};

    auto stage = [&](int step, int bsel) {
        const f16* As = X + Mbase * 256 + step * 32;
        const f16* Bs = win + (size_t)n0 * 256 + step * 32;
        char* base = sm + bsel * 24576;
#pragma unroll
        for (int p = 0; p < 2; ++p) {
            int row = p * 128 + wv * 16 + (lane >> 2);
            __builtin_amdgcn_global_load_lds(
                (const __attribute__((address_space(1))) unsigned int*)(As + (size_t)row * 256 + chs * 8),
                (__attribute__((address_space(3))) unsigned int*)(base + p * 8192 + wv * 1024),
                16, 0, 0);
        }
        {
            int row = wv * 16 + (lane >> 2);
            __builtin_amdgcn_global_load_lds(
                (const __attribute__((address_space(1))) unsigned int*)(Bs + (size_t)row * 256 + chs * 8),
                (__attribute__((address_space(3))) unsigned int*)(base + 16384 + wv * 1024),
                16, 0, 0);
        }
    };
    const int rsl = (g ^ ((c >> 1) & 3)) * 16;   // swizzled 16B slot within 64B row
    auto compute = [&](int bsel) {
        char* base = sm + bsel * 24576;
        half8 a[4], b[4];
#pragma unroll
        for (int mi = 0; mi < 4; ++mi) {
            int row = wm * 64 + mi * 16 + c;
            a[mi] = *(half8*)(base + row * 64 + rsl);
        }
#pragma unroll
        for (int nt = 0; nt < 4; ++nt) {
            int row = wn * 64 + nt * 16 + c;
            b[nt] = *(half8*)(base + 16384 + row * 64 + rsl);
        }
        __builtin_amdgcn_s_setprio(1);
#pragma unroll
        for (int mi = 0; mi < 4; ++mi)
#pragma unroll
            for (int nt = 0; nt < 4; ++nt)
                acc[mi][nt] = MFMA32(a[mi], b[nt], acc[mi][nt]);
        __builtin_amdgcn_s_setprio(0);
    };

    stage(0, 0);
    stage(1, 1);
#pragma unroll
    for (int s = 0; s < 8; ++s) {
        if (s == 7) asm volatile("s_waitcnt vmcnt(0)" ::: "memory");
        else        asm volatile("s_waitcnt vmcnt(3)" ::: "memory");
        __builtin_amdgcn_s_barrier();
        if (s < 6) stage(s + 2, (s + 2) % 3);
        compute(s % 3);
    }

    const f32x4 z4 = {0.f, 0.f, 0.f, 0.f};
    half4 idf;
#pragma unroll
    for (int j = 0; j < 4; ++j) idf[j] = (f16)((g * 4 + j == c) ? 1.f : 0.f);

    if (n0 < 512) {
        // Q,K: transpose via identity mfma, store row-major QK[t][512]
#pragma unroll
        for (int mi = 0; mi < 4; ++mi)
#pragma unroll
            for (int nt = 0; nt < 4; ++nt) {
                int n = n0 + wn * 64 + nt * 16 + c;
                float bias = inb[n];
                half4 h;
#pragma unroll
                for (int r = 0; r < 4; ++r) h[r] = (f16)(acc[mi][nt][r] + bias);
                f32x4 t = MFMA16(h, idf, z4);      // C/D-as-A (=T^T) times I -> transposed tile
                half4 o;
#pragma unroll
                for (int r = 0; r < 4; ++r) o[r] = (f16)t[r];
                size_t tok = Mbase + wm * 64 + mi * 16 + c;       // col of transposed tile = m
                *(half4*)(QK + tok * 512 + (n0 + wn * 64 + nt * 16 + g * 4)) = o;
            }
    } else {
        // V: store [win][d][t] directly from C/D (rows = 4 contiguous tokens)
#pragma unroll
        for (int mi = 0; mi < 4; ++mi)
#pragma unroll
            for (int nt = 0; nt < 4; ++nt) {
                int n = n0 + wn * 64 + nt * 16 + c;
                float bias = inb[n];
                half4 h;
#pragma unroll
                for (int r = 0; r < 4; ++r) h[r] = (f16)(acc[mi][nt][r] + bias);
                int d = n - 512;
                size_t tokb = Mbase + wm * 64 + mi * 16;          // window-aligned
                size_t winI = tokb >> 4;
                *(half4*)(VT + winI * 4096 + (size_t)d * 16 + g * 4) = h;
            }
    }
}

// ---------------- k3a: attention only -> O fragments (MFMA32-B layout) ----------------
// R21->R22 split: 1 window/wave, NO LDS -> occupancy VGPR-bound only; pure TLP hides the
// QK/VT load+softmax latency chains that pinned the fused k3 at ~100us. O frag of lane
// (c,g), head hq, pair p = half8 at O[win*4096 + hq*1024 + p*512 + c*32 + g*8]
// (64 lanes x 16B = contiguous 1KB per (hq,p) -> perfect coalescing both sides).
__global__ __launch_bounds__(256, 2)
void k3a_attn(const f16* __restrict__ QK, const f16* __restrict__ VT,
              f16* __restrict__ O) {
    const int tid = threadIdx.x, lane = tid & 63, wv = tid >> 6;   // 4 waves
    const int c = lane & 15, g = lane >> 4;
    const size_t win = (size_t)blockIdx.x * 4 + wv;
    const f16* qrow = QK + (win * 16 + c) * 512;
    const f32x4 z4 = {0.f, 0.f, 0.f, 0.f};

    half8 ofp[4][2];
#pragma unroll
    for (int hq = 0; hq < 4; ++hq) {
        half8 af0 = *(const half8*)(qrow + 256 + hq * 64 + g * 8);
        half8 af1 = *(const half8*)(qrow + 256 + hq * 64 + 32 + g * 8);
        half8 bq0 = *(const half8*)(qrow + hq * 64 + g * 8);
        half8 bq1 = *(const half8*)(qrow + hq * 64 + 32 + g * 8);
        f32x4 sacc = MFMA32(af0, bq0, z4);     // S^T[k_tok][q]
        sacc = MFMA32(af1, bq1, sacc);
        float s0 = sacc[0] * 0.125f, s1 = sacc[1] * 0.125f;
        float s2 = sacc[2] * 0.125f, s3 = sacc[3] * 0.125f;
        float mx = fmaxf(fmaxf(s0, s1), fmaxf(s2, s3));
        mx = fmaxf(mx, __shfl_xor(mx, 16));
        mx = fmaxf(mx, __shfl_xor(mx, 32));
        float p0 = __expf(s0 - mx), p1 = __expf(s1 - mx);
        float p2 = __expf(s2 - mx), p3 = __expf(s3 - mx);
        float sum = p0 + p1 + p2 + p3;
        sum += __shfl_xor(sum, 16);
        sum += __shfl_xor(sum, 32);
        float inv = 1.f / sum;
        half4 pf;
        pf[0] = (f16)(p0 * inv); pf[1] = (f16)(p1 * inv);
        pf[2] = (f16)(p2 * inv); pf[3] = (f16)(p3 * inv);
#pragma unroll
        for (int nt = 0; nt < 4; ++nt) {
            half4 vf = *(const half4*)(VT + win * 4096 + (size_t)(hq * 64 + nt * 16 + c) * 16 + g * 4);
            f32x4 o = MFMA16(vf, pf, z4);      // O^T[d][q]
#pragma unroll
            for (int r = 0; r < 4; ++r) ofp[hq][nt >> 1][(nt & 1) * 4 + r] = (f16)o[r];
        }
    }
    f16* obase = O + win * 4096 + c * 32 + g * 8;
#pragma unroll
    for (int hq = 0; hq < 4; ++hq)
#pragma unroll
        for (int p = 0; p < 2; ++p)
            *(half8*)(obase + hq * 1024 + p * 512) = ofp[hq][p];
}

// ---------------- k3b: out-proj + proj + GELU -> G[t][256] f16 ----------------
// R21's 16-iter T4+T5 pipeline, attention phase replaced by coalesced O-fragment loads
// (compiler inserts its own waits for these; the counted vmcnt asm only adds constraints).
__global__ __launch_bounds__(256, 2)
void k3b_gemm(const f16* __restrict__ O,
              const f16* __restrict__ wout, const f16* __restrict__ wproj,
              const float* __restrict__ outb, const float* __restrict__ projb,
              f16* __restrict__ G) {
    __shared__ __align__(16) char sm[49152];   // 3 x 16KB weight chunks (k2-geometry image)
    const int tid = threadIdx.x, lane = tid & 63, wv = tid >> 6;   // 4 waves
    const int c = lane & 15, g = lane >> 4;
    const size_t winA = (size_t)blockIdx.x * 8 + wv * 2;
    const size_t winB = winA + 1;
    const f32x4 z4 = {0.f, 0.f, 0.f, 0.f};

    auto stageW = [&](int it, int bsel) {
        const f16* img = (it < 8) ? (wout + it * 8192) : (wproj + (it - 8) * 8192);
#pragma unroll
        for (int q2 = 0; q2 < 4; ++q2) {
            int ia = wv * 4 + q2;
            __builtin_amdgcn_global_load_lds(
                (const __attribute__((address_space(1))) unsigned int*)(img + ia * 512 + lane * 8),
                (__attribute__((address_space(3))) unsigned int*)(sm + bsel * 16384 + ia * 1024),
                16, 0, 0);
        }
    };

    // O fragments for both windows (coalesced 16B loads; VGPR-resident)
    half8 ofpA[4][2], ofpB[4][2];
    const f16* oA = O + winA * 4096 + c * 32 + g * 8;
    const f16* oB = O + winB * 4096 + c * 32 + g * 8;
#pragma unroll
    for (int hq = 0; hq < 4; ++hq)
#pragma unroll
        for (int p = 0; p < 2; ++p) {
            ofpA[hq][p] = *(const half8*)(oA + hq * 1024 + p * 512);
            ofpB[hq][p] = *(const half8*)(oB + hq * 1024 + p * 512);
        }

    stageW(0, 0);
    stageW(1, 1);

    const int rsl = (g ^ ((c >> 1) & 3)) * 16;   // intra-row rotated 16B slot (k2 pattern)
    half8 obpA[8], obpB[8];

    // ---- unified 16-iter pipeline: it 0..7 = out-proj (wout), 8..15 = proj (wproj) ----
#pragma unroll
    for (int it = 0; it < 16; ++it) {
        if (it == 15)     asm volatile("s_waitcnt vmcnt(4)" ::: "memory");
        else if (it >= 9) asm volatile("s_waitcnt vmcnt(8)" ::: "memory");
        else              asm volatile("s_waitcnt vmcnt(4)" ::: "memory");
        __builtin_amdgcn_s_barrier();
        if (it < 14) stageW(it + 2, (it + 2) % 3);
        char* base = sm + (it % 3) * 16384;
        f32x4 aA0 = z4, aA1 = z4, aB0 = z4, aB1 = z4;
        __builtin_amdgcn_s_setprio(1);
        if (it < 8) {
#pragma unroll
            for (int kc = 0; kc < 8; ++kc) {
                half8 w0 = *(half8*)(base + kc * 2048 + c * 64 + rsl);
                aA0 = MFMA32(w0, ofpA[kc >> 1][kc & 1], aA0);
                aB0 = MFMA32(w0, ofpB[kc >> 1][kc & 1], aB0);
                half8 w1 = *(half8*)(base + kc * 2048 + 1024 + c * 64 + rsl);
                aA1 = MFMA32(w1, ofpA[kc >> 1][kc & 1], aA1);
                aB1 = MFMA32(w1, ofpB[kc >> 1][kc & 1], aB1);
            }
        } else {
#pragma unroll
            for (int kc = 0; kc < 8; ++kc) {
                half8 w0 = *(half8*)(base + kc * 2048 + c * 64 + rsl);
                aA0 = MFMA32(w0, obpA[kc], aA0);
                aB0 = MFMA32(w0, obpB[kc], aB0);
                half8 w1 = *(half8*)(base + kc * 2048 + 1024 + c * 64 + rsl);
                aA1 = MFMA32(w1, obpA[kc], aA1);
                aB1 = MFMA32(w1, obpB[kc], aB1);
            }
        }
        __builtin_amdgcn_s_setprio(0);
        if (it < 8) {
            const int ch = it;
            f32x4 b0 = *(const f32x4*)(outb + ch * 32 + g * 4);
            f32x4 b1 = *(const f32x4*)(outb + ch * 32 + 16 + g * 4);
#pragma unroll
            for (int r = 0; r < 4; ++r) {
                obpA[ch][r]     = (f16)(aA0[r] + b0[r]);
                obpA[ch][4 + r] = (f16)(aA1[r] + b1[r]);
                obpB[ch][r]     = (f16)(aB0[r] + b0[r]);
                obpB[ch][4 + r] = (f16)(aB1[r] + b1[r]);
            }
        } else {
            const int pc = it - 8;
            f32x4 b0 = *(const f32x4*)(projb + pc * 32 + g * 4);
            f32x4 b1 = *(const f32x4*)(projb + pc * 32 + 16 + g * 4);
            half4 hA0, hA1, hB0, hB1;
#pragma unroll
            for (int r = 0; r < 4; ++r) {
                hA0[r] = (f16)gelu_f(aA0[r] + b0[r]);
                hA1[r] = (f16)gelu_f(aA1[r] + b1[r]);
                hB0[r] = (f16)gelu_f(aB0[r] + b0[r]);
                hB1[r] = (f16)gelu_f(aB1[r] + b1[r]);
            }
            f16* growA = G + (winA * 16 + c) * 256 + pc * 32;
            *(half4*)(growA + g * 4) = hA0;
            *(half4*)(growA + 16 + g * 4) = hA1;
            f16* growB = G + (winB * 16 + c) * 256 + pc * 32;
            *(half4*)(growB + g * 4) = hB0;
            *(half4*)(growB + 16 + g * 4) = hB1;
        }
    }
}

// ---------------- k4: residual + NCHW scatter, one block per full (bb,h) row ----------------
__global__ __launch_bounds__(256, 8)
void k4_out(const f16* __restrict__ G, const float* __restrict__ feat, float* __restrict__ outp) {
    const int tid = threadIdx.x;
    const int bid = blockIdx.x;            // bb*127 + h
    const int bb = bid / 127, h = bid % 127;
    const int w = tid & 127;               // 0..127 (w==127 masked: pad column)
    const int cq = tid >> 7;               // 0..1
    const bool wok = (w < 127);
    const size_t bbase = (size_t)bb * (256 * 127 * 127);
    const int wi = h >> 2, hh = h & 3;
    const int jh = w >> 5, wl4 = (w >> 2) & 7, e = w & 3;
    const size_t t = ((size_t)((bb * 32 + wi) * 4 + jh)) * 128 + wl4 * 16 + hh * 4 + e;
    const f16* gp = G + t * 256;
    const float* fp = feat + bbase + (size_t)h * 127 + w;
    float* op = outp + bbase + (size_t)h * 127 + w;
#pragma unroll 4
    for (int ci = 0; ci < 32; ++ci) {
        const int ch = ci * 8 + cq * 4;
        if (wok) {
            half4 g4 = *(const half4*)(gp + ch);
#pragma unroll
            for (int j = 0; j < 4; ++j) {
                size_t off = (size_t)(ch + j) * 16129;
                op[off] = fp[off] + (float)g4[j];
            }
        }
    }
}

extern "C" void kernel_launch(void* const* d_in, const int* in_sizes, int n_in,
                              void* d_out, int out_size, void* d_ws, size_t ws_size,
                              hipStream_t stream) {
    const float* feat   = (const float*)d_in[0];
    const float* ln_w   = (const float*)d_in[1];
    const float* ln_b   = (const float*)d_in[2];
    const float* in_w   = (const float*)d_in[3];
    const float* in_b   = (const float*)d_in[4];
    const float* out_w  = (const float*)d_in[5];
    const float* out_b  = (const float*)d_in[6];
    const float* proj_w = (const float*)d_in[7];
    const float* proj_b = (const float*)d_in[8];

    f16* W   = (f16*)d_ws;
    f16* Xb  = W + X0;     // X, then O (X dead after k2)
    f16* QKb = W + QK0;    // QK, then G (QK dead after k3a)
    f16* VTb = W + VT0;

    k0_cast<<<768, 256, 0, stream>>>(in_w, out_w, proj_w, W);
    k1_pack<<<1024, 256, 0, stream>>>(feat, ln_w, ln_b, Xb);
    k2_qkv<<<3072, 512, 0, stream>>>(Xb, W + W_IN0, in_b, QKb, VTb);
    k3a_attn<<<2048, 256, 0, stream>>>(QKb, VTb, Xb);
    k3b_gemm<<<1024, 256, 0, stream>>>(Xb, W + W_OUT0, W + W_PROJ0, out_b, proj_b, QKb);
    k4_out<<<1016, 256, 0, stream>>>(QKb, feat, (float*)d_out);
}

// Round 23
// 328.153 us; speedup vs baseline: 1.1247x; 1.1247x over previous
//
#include <hip/hip_runtime.h>

typedef _Float16 f16;
typedef __attribute__((ext_vector_type(4))) _Float16 half4;
typedef __attribute__((ext_vector_type(8))) _Float16 half8;
typedef __attribute__((ext_vector_type(4))) float f32x4;
typedef unsigned short u16;

#define MFMA32(a,b,c) __builtin_amdgcn_mfma_f32_16x16x32_f16(a,b,c,0,0,0)
#define MFMA16(a,b,c) __builtin_amdgcn_mfma_f32_16x16x16f16(a,b,c,0,0,0)

// ws layout (f16 element offsets)
#define W_IN0   0
#define W_OUT0  196608
#define W_PROJ0 262144
#define X0      327680
#define QK0     33882112ull
#define VT0     100990976ull

// exact-grade GELU: erf via A&S 7.1.26 (|eps|<=1.5e-7)
__device__ __forceinline__ float gelu_f(float x) {
    float z = x * 0.70710678118f;
    float az = fabsf(z);
    float t = 1.f / (1.f + 0.3275911f * az);
    float e = __expf(-z * z);
    float poly = ((((1.061405429f * t - 1.453152027f) * t + 1.421413741f) * t
                   - 0.284496736f) * t + 0.254829592f) * t;
    float er = 1.f - poly * e;
    er = copysignf(er, z);
    return 0.5f * x * (1.f + er);
}

// ---------------- k0: cast weights to f16; build k2-geometry images for w_out/w_proj ----
__global__ void k0_cast(const float* __restrict__ iw, const float* __restrict__ ow,
                        const float* __restrict__ pw, f16* __restrict__ W) {
    int i = blockIdx.x * 256 + threadIdx.x;
    if (i < 196608) W[W_IN0 + i] = (f16)iw[i];
    if (i < 16384) {
        const int s = i & 8191;
        const float* src = (i < 8192) ? ow : pw;
        f16* dst = W + ((i < 8192) ? W_OUT0 : W_PROJ0);
        const int g  = s & 3;
        const int r  = (s >> 2) & 31;
        const int kc = (s >> 7) & 7;
        const int ch = s >> 10;
        const int R = ch * 32 + r;
        const int c0 = kc * 32 + g * 4;
        f32x4 v0 = *(const f32x4*)(src + R * 256 + c0);
        f32x4 v1 = *(const f32x4*)(src + R * 256 + c0 + 16);
        half8 o;
#pragma unroll
        for (int j = 0; j < 4; ++j) { o[j] = (f16)v0[j]; o[j + 4] = (f16)v1[j]; }
        const int sg = g ^ ((r >> 1) & 3);
        *(half8*)(dst + ch * 8192 + kc * 1024 + r * 32 + sg * 8) = o;
    }
}

// ---------------- k1: NCHW gather + LayerNorm -> X[t][256] f16, k4-geometry ----------------
__global__ __launch_bounds__(256, 2)
void k1_pack(const float* __restrict__ feat, const float* __restrict__ lnw,
             const float* __restrict__ lnb, f16* __restrict__ X) {
    __shared__ float redS[256], redQ[256];
    const int tid = threadIdx.x;
    const int w = tid & 127, cq = tid >> 7;
    const int bid = blockIdx.x;
    const int bb = bid >> 7, h = bid & 127;
    const int c0 = cq * 128;
    const bool ok = (h < 127) && (w < 127);
    const size_t bbase = (size_t)bb * (256 * 127 * 127);
    const float* p0 = feat + bbase + (size_t)c0 * 16129 + (size_t)h * 127 + w;

    half8 ov[16];                      // 128 channels as f16
    float s = 0.f, s2 = 0.f;
    if (ok) {
#pragma unroll
        for (int i = 0; i < 16; ++i) {
            half8 hv;
#pragma unroll
            for (int j = 0; j < 8; ++j) {
                float v = p0[(size_t)(i * 8 + j) * 16129];
                s += v; s2 += v * v; hv[j] = (f16)v;
            }
            ov[i] = hv;
        }
    } else {
#pragma unroll
        for (int i = 0; i < 16; ++i) {
            half8 hv;
#pragma unroll
            for (int j = 0; j < 8; ++j) hv[j] = (f16)0.f;
            ov[i] = hv;
        }
    }
    redS[tid] = s; redQ[tid] = s2;
    __syncthreads();
    float st = redS[w] + redS[w + 128];
    float qt = redQ[w] + redQ[w + 128];
    float mu = st * (1.f / 256.f);
    float rs = rsqrtf(qt * (1.f / 256.f) - mu * mu + 1e-5f);

    const int wi = h >> 2, hh = h & 3;
    const int jh = w >> 5, wl4 = (w >> 2) & 7, e = w & 3;
    const size_t t = ((size_t)((bb * 32 + wi) * 4 + jh)) * 128 + wl4 * 16 + hh * 4 + e;
    f16* xrow = X + t * 256 + c0;
#pragma unroll
    for (int i = 0; i < 16; ++i) {
        f32x4 lw0 = *(const f32x4*)(lnw + c0 + i * 8);
        f32x4 lw1 = *(const f32x4*)(lnw + c0 + i * 8 + 4);
        f32x4 lb0 = *(const f32x4*)(lnb + c0 + i * 8);
        f32x4 lb1 = *(const f32x4*)(lnb + c0 + i * 8 + 4);
        half8 o;
#pragma unroll
        for (int j = 0; j < 4; ++j) {
            o[j]     = (f16)(((float)ov[i][j]     - mu) * rs * lw0[j] + lb0[j]);
            o[j + 4] = (f16)(((float)ov[i][j + 4] - mu) * rs * lw1[j] + lb1[j]);
        }
        *(half8*)(xrow + i * 8) = o;
    }
}

// ---------------- k2: QKV GEMM  X[131072x256] @ in_w^T -> QK / VT ----------------
// T4 pipeline (triple buffer, counted vmcnt, raw barrier) + T5 setprio (frozen).
__global__ __launch_bounds__(512, 2)
void k2_qkv(const f16* __restrict__ X, const f16* __restrict__ win,
            const float* __restrict__ inb, f16* __restrict__ QK, f16* __restrict__ VT) {
    __shared__ __align__(16) char sm[73728];   // 3 bufs x (A 16K | B 8K)
    const int tid = threadIdx.x, lane = tid & 63, wv = tid >> 6;   // 8 waves
    const int nwg = gridDim.x;                 // 3072, divisible by 8
    const int bid = (blockIdx.x & 7) * (nwg >> 3) + (blockIdx.x >> 3);
    const int mt = bid / 6, nb = bid % 6;
    const size_t Mbase = (size_t)mt * 256;
    const int n0 = nb * 128;
    const int wm = wv >> 1, wn = wv & 1;       // 4 M-groups x 2 N-groups
    const int c = lane & 15, g = lane >> 4;
    const int chs = (lane & 3) ^ ((lane >> 3) & 3);   // involution source chunk

    f32x4 acc[4][4];
#pragma unroll
    for (int a = 0; a < 4; ++a)
#pragma unroll
        for (int b = 0; b < 4; ++b) acc[a][b] = f32x4{0.f, 0.f, 0.f, 0.f};

    auto stage = [&](int step, int bsel) {
        const f16* As = X + Mbase * 256 + step * 32;
        const f16* Bs = win + (size_t)n0 * 256 + step * 32;
        char* base = sm + bsel * 24576;
#pragma unroll
        for (int p = 0; p < 2; ++p) {
            int row = p * 128 + wv * 16 + (lane >> 2);
            __builtin_amdgcn_global_load_lds(
                (const __attribute__((address_space(1))) unsigned int*)(As + (size_t)row * 256 + chs * 8),
                (__attribute__((address_space(3))) unsigned int*)(base + p * 8192 + wv * 1024),
                16, 0, 0);
        }
        {
            int row = wv * 16 + (lane >> 2);
            __builtin_amdgcn_global_load_lds(
                (const __attribute__((address_space(1))) unsigned int*)(Bs + (size_t)row * 256 + chs * 8),
                (__attribute__((address_space(3))) unsigned int*)(base + 16384 + wv * 1024),
                16, 0, 0);
        }
    };
    const int rsl = (g ^ ((c >> 1) & 3)) * 16;   // swizzled 16B slot within 64B row
    auto compute = [&](int bsel) {
        char* base = sm + bsel * 24576;
        half8 a[4], b[4];
#pragma unroll
        for (int mi = 0; mi < 4; ++mi) {
            int row = wm * 64 + mi * 16 + c;
            a[mi] = *(half8*)(base + row * 64 + rsl);
        }
#pragma unroll
        for (int nt = 0; nt < 4; ++nt) {
            int row = wn * 64 + nt * 16 + c;
            b[nt] = *(half8*)(base + 16384 + row * 64 + rsl);
        }
        __builtin_amdgcn_s_setprio(1);
#pragma unroll
        for (int mi = 0; mi < 4; ++mi)
#pragma unroll
            for (int nt = 0; nt < 4; ++nt)
                acc[mi][nt] = MFMA32(a[mi], b[nt], acc[mi][nt]);
        __builtin_amdgcn_s_setprio(0);
    };

    stage(0, 0);
    stage(1, 1);
#pragma unroll
    for (int s = 0; s < 8; ++s) {
        if (s == 7) asm volatile("s_waitcnt vmcnt(0)" ::: "memory");
        else        asm volatile("s_waitcnt vmcnt(3)" ::: "memory");
        __builtin_amdgcn_s_barrier();
        if (s < 6) stage(s + 2, (s + 2) % 3);
        compute(s % 3);
    }

    const f32x4 z4 = {0.f, 0.f, 0.f, 0.f};
    half4 idf;
#pragma unroll
    for (int j = 0; j < 4; ++j) idf[j] = (f16)((g * 4 + j == c) ? 1.f : 0.f);

    if (n0 < 512) {
        // Q,K: transpose via identity mfma, store row-major QK[t][512]
#pragma unroll
        for (int mi = 0; mi < 4; ++mi)
#pragma unroll
            for (int nt = 0; nt < 4; ++nt) {
                int n = n0 + wn * 64 + nt * 16 + c;
                float bias = inb[n];
                half4 h;
#pragma unroll
                for (int r = 0; r < 4; ++r) h[r] = (f16)(acc[mi][nt][r] + bias);
                f32x4 t = MFMA16(h, idf, z4);      // C/D-as-A (=T^T) times I -> transposed tile
                half4 o;
#pragma unroll
                for (int r = 0; r < 4; ++r) o[r] = (f16)t[r];
                size_t tok = Mbase + wm * 64 + mi * 16 + c;       // col of transposed tile = m
                *(half4*)(QK + tok * 512 + (n0 + wn * 64 + nt * 16 + g * 4)) = o;
            }
    } else {
        // V: store [win][d][t] directly from C/D (rows = 4 contiguous tokens)
#pragma unroll
        for (int mi = 0; mi < 4; ++mi)
#pragma unroll
            for (int nt = 0; nt < 4; ++nt) {
                int n = n0 + wn * 64 + nt * 16 + c;
                float bias = inb[n];
                half4 h;
#pragma unroll
                for (int r = 0; r < 4; ++r) h[r] = (f16)(acc[mi][nt][r] + bias);
                int d = n - 512;
                size_t tokb = Mbase + wm * 64 + mi * 16;          // window-aligned
                size_t winI = tokb >> 4;
                *(half4*)(VT + winI * 4096 + (size_t)d * 16 + g * 4) = h;
            }
    }
}

// ---------------- k3: attention + out-proj + proj + GELU -> G[t][256] f16 (R21 fused) ----
// R22's split regressed (+36us: O round-trip 128MB + lost overlap) -> revert to fused.
__global__ __launch_bounds__(256, 2)
void k3_attn(const f16* __restrict__ QK, const f16* __restrict__ VT,
             const f16* __restrict__ wout, const f16* __restrict__ wproj,
             const float* __restrict__ outb, const float* __restrict__ projb,
             f16* __restrict__ G) {
    __shared__ __align__(16) char sm[49152];   // 3 x 16KB weight chunks (k2-geometry image)
    const int tid = threadIdx.x, lane = tid & 63, wv = tid >> 6;   // 4 waves
    const int c = lane & 15, g = lane >> 4;
    const size_t winA = (size_t)blockIdx.x * 8 + wv * 2;
    const size_t winB = winA + 1;
    const f16* qrowA = QK + (winA * 16 + c) * 512;
    const f16* qrowB = QK + (winB * 16 + c) * 512;
    const f32x4 z4 = {0.f, 0.f, 0.f, 0.f};

    auto stageW = [&](int it, int bsel) {
        const f16* img = (it < 8) ? (wout + it * 8192) : (wproj + (it - 8) * 8192);
#pragma unroll
        for (int q2 = 0; q2 < 4; ++q2) {
            int ia = wv * 4 + q2;
            __builtin_amdgcn_global_load_lds(
                (const __attribute__((address_space(1))) unsigned int*)(img + ia * 512 + lane * 8),
                (__attribute__((address_space(3))) unsigned int*)(sm + bsel * 16384 + ia * 1024),
                16, 0, 0);
        }
    };

    stageW(0, 0);
    stageW(1, 1);

    // ---- attention for both windows; pack PV outputs as MFMA32 B-frags ----
    half8 ofpA[4][2], ofpB[4][2];
#pragma unroll
    for (int wsel = 0; wsel < 2; ++wsel) {
        const f16* qrow = wsel ? qrowB : qrowA;
        const size_t wn_ = wsel ? winB : winA;
#pragma unroll
        for (int hq = 0; hq < 4; ++hq) {
            half8 af0 = *(const half8*)(qrow + 256 + hq * 64 + g * 8);
            half8 af1 = *(const half8*)(qrow + 256 + hq * 64 + 32 + g * 8);
            half8 bq0 = *(const half8*)(qrow + hq * 64 + g * 8);
            half8 bq1 = *(const half8*)(qrow + hq * 64 + 32 + g * 8);
            f32x4 sacc = MFMA32(af0, bq0, z4);     // S^T[k_tok][q]
            sacc = MFMA32(af1, bq1, sacc);
            float s0 = sacc[0] * 0.125f, s1 = sacc[1] * 0.125f;
            float s2 = sacc[2] * 0.125f, s3 = sacc[3] * 0.125f;
            float mx = fmaxf(fmaxf(s0, s1), fmaxf(s2, s3));
            mx = fmaxf(mx, __shfl_xor(mx, 16));
            mx = fmaxf(mx, __shfl_xor(mx, 32));
            float p0 = __expf(s0 - mx), p1 = __expf(s1 - mx);
            float p2 = __expf(s2 - mx), p3 = __expf(s3 - mx);
            float sum = p0 + p1 + p2 + p3;
            sum += __shfl_xor(sum, 16);
            sum += __shfl_xor(sum, 32);
            float inv = 1.f / sum;
            half4 pf;
            pf[0] = (f16)(p0 * inv); pf[1] = (f16)(p1 * inv);
            pf[2] = (f16)(p2 * inv); pf[3] = (f16)(p3 * inv);
#pragma unroll
            for (int nt = 0; nt < 4; ++nt) {
                half4 vf = *(const half4*)(VT + wn_ * 4096 + (size_t)(hq * 64 + nt * 16 + c) * 16 + g * 4);
                f32x4 o = MFMA16(vf, pf, z4);      // O^T[d][q]
#pragma unroll
                for (int r = 0; r < 4; ++r) {
                    if (wsel) ofpB[hq][nt >> 1][(nt & 1) * 4 + r] = (f16)o[r];
                    else      ofpA[hq][nt >> 1][(nt & 1) * 4 + r] = (f16)o[r];
                }
            }
        }
    }

    const int rsl = (g ^ ((c >> 1) & 3)) * 16;   // intra-row rotated 16B slot (k2 pattern)
    half8 obpA[8], obpB[8];

    // ---- unified 16-iter pipeline: it 0..7 = out-proj (wout), 8..15 = proj (wproj) ----
#pragma unroll
    for (int it = 0; it < 16; ++it) {
        if (it == 15)     asm volatile("s_waitcnt vmcnt(4)" ::: "memory");
        else if (it >= 9) asm volatile("s_waitcnt vmcnt(8)" ::: "memory");
        else              asm volatile("s_waitcnt vmcnt(4)" ::: "memory");
        __builtin_amdgcn_s_barrier();
        if (it < 14) stageW(it + 2, (it + 2) % 3);
        char* base = sm + (it % 3) * 16384;
        f32x4 aA0 = z4, aA1 = z4, aB0 = z4, aB1 = z4;
        __builtin_amdgcn_s_setprio(1);
        if (it < 8) {
#pragma unroll
            for (int kc = 0; kc < 8; ++kc) {
                half8 w0 = *(half8*)(base + kc * 2048 + c * 64 + rsl);
                aA0 = MFMA32(w0, ofpA[kc >> 1][kc & 1], aA0);
                aB0 = MFMA32(w0, ofpB[kc >> 1][kc & 1], aB0);
                half8 w1 = *(half8*)(base + kc * 2048 + 1024 + c * 64 + rsl);
                aA1 = MFMA32(w1, ofpA[kc >> 1][kc & 1], aA1);
                aB1 = MFMA32(w1, ofpB[kc >> 1][kc & 1], aB1);
            }
        } else {
#pragma unroll
            for (int kc = 0; kc < 8; ++kc) {
                half8 w0 = *(half8*)(base + kc * 2048 + c * 64 + rsl);
                aA0 = MFMA32(w0, obpA[kc], aA0);
                aB0 = MFMA32(w0, obpB[kc], aB0);
                half8 w1 = *(half8*)(base + kc * 2048 + 1024 + c * 64 + rsl);
                aA1 = MFMA32(w1, obpA[kc], aA1);
                aB1 = MFMA32(w1, obpB[kc], aB1);
            }
        }
        __builtin_amdgcn_s_setprio(0);
        if (it < 8) {
            const int ch = it;
            f32x4 b0 = *(const f32x4*)(outb + ch * 32 + g * 4);
            f32x4 b1 = *(const f32x4*)(outb + ch * 32 + 16 + g * 4);
#pragma unroll
            for (int r = 0; r < 4; ++r) {
                obpA[ch][r]     = (f16)(aA0[r] + b0[r]);
                obpA[ch][4 + r] = (f16)(aA1[r] + b1[r]);
                obpB[ch][r]     = (f16)(aB0[r] + b0[r]);
                obpB[ch][4 + r] = (f16)(aB1[r] + b1[r]);
            }
        } else {
            const int pc = it - 8;
            f32x4 b0 = *(const f32x4*)(projb + pc * 32 + g * 4);
            f32x4 b1 = *(const f32x4*)(projb + pc * 32 + 16 + g * 4);
            half4 hA0, hA1, hB0, hB1;
#pragma unroll
            for (int r = 0; r < 4; ++r) {
                hA0[r] = (f16)gelu_f(aA0[r] + b0[r]);
                hA1[r] = (f16)gelu_f(aA1[r] + b1[r]);
                hB0[r] = (f16)gelu_f(aB0[r] + b0[r]);
                hB1[r] = (f16)gelu_f(aB1[r] + b1[r]);
            }
            f16* growA = G + (winA * 16 + c) * 256 + pc * 32;
            *(half4*)(growA + g * 4) = hA0;
            *(half4*)(growA + 16 + g * 4) = hA1;
            f16* growB = G + (winB * 16 + c) * 256 + pc * 32;
            *(half4*)(growB + g * 4) = hB0;
            *(half4*)(growB + 16 + g * 4) = hB1;
        }
    }
}

// ---------------- k4: residual + NCHW scatter, one block per full (bb,h) row ----------------
// R22->R23: launch_bounds (256,8)->(256,4). Grid is only 1016 blocks (~4/CU) so the
// 8-blocks/CU cap bought nothing but a 64-reg budget (VGPR_Count 28 -> ~6 loads in
// flight, latency-bound at 3.4 TB/s). 128-reg budget lets the compiler keep 16-24
// independent scalar loads outstanding. (4th instance of the launch-bounds trap.)
__global__ __launch_bounds__(256, 4)
void k4_out(const f16* __restrict__ G, const float* __restrict__ feat, float* __restrict__ outp) {
    const int tid = threadIdx.x;
    const int bid = blockIdx.x;            // bb*127 + h
    const int bb = bid / 127, h = bid % 127;
    const int w = tid & 127;               // 0..127 (w==127 masked: pad column)
    const int cq = tid >> 7;               // 0..1
    const bool wok = (w < 127);
    const size_t bbase = (size_t)bb * (256 * 127 * 127);
    const int wi = h >> 2, hh = h & 3;
    const int jh = w >> 5, wl4 = (w >> 2) & 7, e = w & 3;
    const size_t t = ((size_t)((bb * 32 + wi) * 4 + jh)) * 128 + wl4 * 16 + hh * 4 + e;
    const f16* gp = G + t * 256;
    const float* fp = feat + bbase + (size_t)h * 127 + w;
    float* op = outp + bbase + (size_t)h * 127 + w;
#pragma unroll 8
    for (int ci = 0; ci < 32; ++ci) {
        const int ch = ci * 8 + cq * 4;
        if (wok) {
            half4 g4 = *(const half4*)(gp + ch);
#pragma unroll
            for (int j = 0; j < 4; ++j) {
                size_t off = (size_t)(ch + j) * 16129;
                op[off] = fp[off] + (float)g4[j];
            }
        }
    }
}

extern "C" void kernel_launch(void* const* d_in, const int* in_sizes, int n_in,
                              void* d_out, int out_size, void* d_ws, size_t ws_size,
                              hipStream_t stream) {
    const float* feat   = (const float*)d_in[0];
    const float* ln_w   = (const float*)d_in[1];
    const float* ln_b   = (const float*)d_in[2];
    const float* in_w   = (const float*)d_in[3];
    const float* in_b   = (const float*)d_in[4];
    const float* out_w  = (const float*)d_in[5];
    const float* out_b  = (const float*)d_in[6];
    const float* proj_w = (const float*)d_in[7];
    const float* proj_b = (const float*)d_in[8];

    f16* W   = (f16*)d_ws;
    f16* Xb  = W + X0;
    f16* QKb = W + QK0;
    f16* VTb = W + VT0;
    f16* Gb  = Xb;   // reuse X region for G (X dead after k2)

    k0_cast<<<768, 256, 0, stream>>>(in_w, out_w, proj_w, W);
    k1_pack<<<1024, 256, 0, stream>>>(feat, ln_w, ln_b, Xb);
    k2_qkv<<<3072, 512, 0, stream>>>(Xb, W + W_IN0, in_b, QKb, VTb);
    k3_attn<<<1024, 256, 0, stream>>>(QKb, VTb, W + W_OUT0, W + W_PROJ0, out_b, proj_b, Gb);
    k4_out<<<1016, 256, 0, stream>>>(Gb, feat, (float*)d_out);
}